// Round 11
// baseline (661.263 us; speedup 1.0000x reference)
//
#include <hip/hip_runtime.h>
#include <math.h>

#define NN 50000
#define NREL 400
#define NLAYERS 3

static __device__ __forceinline__ float clip15(float x) { return fminf(fmaxf(x, -15.f), 15.f); }

// ---------------- CSR build ----------------
__global__ void count_k(const int* __restrict__ dst, int* __restrict__ deg, int E) {
  int e = blockIdx.x * blockDim.x + threadIdx.x;
  if (e < E) atomicAdd(&deg[dst[e]], 1);
}

__global__ void scan_k(const int* __restrict__ deg, int* __restrict__ start, int* __restrict__ cursor,
                       int* __restrict__ counter, float* __restrict__ logsum, int N) {
  int n = blockIdx.x * blockDim.x + threadIdx.x;
  int lane = threadIdx.x & 63;
  int d = (n < N) ? deg[n] : 0;
  int pre = d;
  #pragma unroll
  for (int off = 1; off < 64; off <<= 1) { int t = __shfl_up(pre, off); if (lane >= off) pre += t; }
  int base = 0;
  if (lane == 63) base = atomicAdd(counter, pre);
  base = __shfl(base, 63);
  if (n < N) { int pos = base + pre - d; start[n] = pos; cursor[n] = pos; }
  float v = (n < N) ? logf((float)d + 1.0f) : 0.f;
  #pragma unroll
  for (int off = 32; off; off >>= 1) v += __shfl_xor(v, off);
  if (lane == 0) atomicAdd(logsum, v);
}

__global__ void scale_k(const int* __restrict__ deg, const float* __restrict__ logsum,
                        float* __restrict__ scale, int N) {
  int n = blockIdx.x * blockDim.x + threadIdx.x;
  if (n < N) scale[n] = logf((float)deg[n] + 1.0f) * (float)N / logsum[0];
}

__global__ void scatter_k(const int* __restrict__ src, const int* __restrict__ dst,
                          const int* __restrict__ typ, int* __restrict__ cursor,
                          int2* __restrict__ csr, int E) {
  int e = blockIdx.x * blockDim.x + threadIdx.x;
  if (e < E) {
    int dd = dst[e];
    int pos = atomicAdd(&cursor[dd], 1);
    csr[pos] = make_int2(src[e], typ[e]);
  }
}

// ---------------- init ----------------
// scalars layout: [0..63]=c_q (lin_b + q @ lin_W[64:128]) ; [64]=zero_s ; [65]=head_s
__global__ void prep_k(const float* __restrict__ head_embeds, const float* __restrict__ rel_table,
                       const float* __restrict__ lin_W, const float* __restrict__ lin_b,
                       const float* __restrict__ mlp_W1, const float* __restrict__ mlp_b1,
                       const float* __restrict__ mlp_W2, const float* __restrict__ mlp_b2,
                       const int* __restrict__ head_index, const int* __restrict__ r_index,
                       float* __restrict__ hidden, float* __restrict__ scalars) {
  int j = threadIdx.x;  // 0..63
  int r = r_index[0], hd = head_index[0];
  float qj = rel_table[r * 64 + j];
  float cq = lin_b[j];
  for (int k = 0; k < 64; ++k) cq += __shfl(qj, k) * lin_W[(64 + k) * 64 + j];
  scalars[j] = cq;
  // zero score: x = 0 -> h1 = relu(b1)
  float t = fmaxf(mlp_b1[j], 0.f) * mlp_W2[j] + fmaxf(mlp_b1[64 + j], 0.f) * mlp_W2[64 + j];
  #pragma unroll
  for (int off = 32; off; off >>= 1) t += __shfl_xor(t, off);
  float zs = clip15(t + mlp_b2[0]);
  // head node
  float hj = head_embeds[j];
  hidden[(size_t)hd * 64 + j] = hj;
  float heur = cq;
  for (int k = 0; k < 64; ++k) heur += __shfl(hj, k) * lin_W[k * 64 + j];
  float xj = hj * heur;
  float h1a = mlp_b1[j], h1b = mlp_b1[64 + j];
  for (int k = 0; k < 64; ++k) {
    float xk = __shfl(xj, k);
    h1a += xk * mlp_W1[k * 128 + j];
    h1b += xk * mlp_W1[k * 128 + 64 + j];
  }
  h1a = fmaxf(h1a, 0.f); h1b = fmaxf(h1b, 0.f);
  float p = h1a * mlp_W2[j] + h1b * mlp_W2[64 + j];
  #pragma unroll
  for (int off = 32; off; off >>= 1) p += __shfl_xor(p, off);
  float hs = clip15(p + mlp_b2[0]);
  if (j == 0) { scalars[64] = zs; scalars[65] = hs; }
}

__global__ void fill_k(float* __restrict__ score, const float* __restrict__ scalars,
                       const int* __restrict__ head_index, int N) {
  int n = blockIdx.x * blockDim.x + threadIdx.x;
  if (n < N) score[n] = (n == head_index[0]) ? scalars[65] : scalars[64];
}

// ---------------- per-layer ----------------
// agg_k with fused gate: per edge, g = sigmoid(score[src]); li = g * hidden[src];
// msg = li * relW[type]. Eliminates gate_k dispatch and the LI buffer round-trip.
// (g*h rounds identically to the staged version -> bitwise-same results.)
__global__ __launch_bounds__(256) void agg_k(const float* __restrict__ hidden, const float* __restrict__ score,
                                             const int2* __restrict__ csr,
                                             const int* __restrict__ start, const int* __restrict__ deg,
                                             const float* __restrict__ relW, float* __restrict__ f1, int N) {
  int wid = threadIdx.x >> 6;
  int lane = threadIdx.x & 63;
  int node = blockIdx.x * 4 + wid;
  if (node >= N) return;
  int base = start[node], d = deg[node];
  float sum = 0.f, sq = 0.f, mx = -3.402823e38f, mn = 3.402823e38f;
  int e = 0;
  for (; e + 4 <= d; e += 4) {
    int2 p0 = csr[base + e], p1 = csr[base + e + 1];
    int2 p2 = csr[base + e + 2], p3 = csr[base + e + 3];
    float g0 = 1.f / (1.f + expf(-score[p0.x]));
    float g1 = 1.f / (1.f + expf(-score[p1.x]));
    float g2 = 1.f / (1.f + expf(-score[p2.x]));
    float g3 = 1.f / (1.f + expf(-score[p3.x]));
    float a0 = g0 * hidden[p0.x * 64 + lane], w0 = relW[p0.y * 64 + lane];
    float a1 = g1 * hidden[p1.x * 64 + lane], w1 = relW[p1.y * 64 + lane];
    float a2 = g2 * hidden[p2.x * 64 + lane], w2 = relW[p2.y * 64 + lane];
    float a3 = g3 * hidden[p3.x * 64 + lane], w3 = relW[p3.y * 64 + lane];
    float m0 = a0 * w0, m1 = a1 * w1, m2 = a2 * w2, m3 = a3 * w3;
    sum += (m0 + m1) + (m2 + m3);
    sq += (m0 * m0 + m1 * m1) + (m2 * m2 + m3 * m3);
    mx = fmaxf(fmaxf(mx, fmaxf(m0, m1)), fmaxf(m2, m3));
    mn = fminf(fminf(mn, fminf(m0, m1)), fminf(m2, m3));
  }
  for (; e < d; ++e) {
    int2 p = csr[base + e];
    float g = 1.f / (1.f + expf(-score[p.x]));
    float li = g * hidden[p.x * 64 + lane];
    float m = li * relW[p.y * 64 + lane];
    sum += m; sq += m * m; mx = fmaxf(mx, m); mn = fminf(mn, m);
  }
  float* out = f1 + (size_t)node * 256;
  if (d > 0) {
    float inv = 1.0f / (float)d;
    float mean = sum * inv, sqm = sq * inv;
    float sd = sqrtf(fmaxf(sqm - mean * mean, 0.f) + 1e-6f);
    out[lane] = mean; out[64 + lane] = mx; out[128 + lane] = mn; out[192 + lane] = sd;
  } else {
    out[lane] = 0.f; out[64 + lane] = 0.f; out[128 + lane] = 0.f; out[192 + lane] = 0.f;
  }
}

// update = f1 @ Wa + scale*(f1 @ Wb) + b ; hidden += update (deg>0)
// LDS-ISSUE-BOUND fix (r10 post-mortem): 128 threads, thread = 8 nodes x 4 outs x {a,b}.
// Per kk per wave: 4x ds_read_b128 (48 cyc) feeds 64 FMA (128 cyc) -> ratio 2.7:1
// (was 1.07:1 -> LDS pipe saturated at ~184k cyc/CU, VALUBusy capped at 35%).
// LDS 25 KB -> 6 blocks/CU x 2 waves = 12 waves/CU; grid 782 unchanged.
__global__ __launch_bounds__(128) void gemm_k(const float* __restrict__ f1, const float* __restrict__ aggW,
                                              const float* __restrict__ aggb, const float* __restrict__ scale,
                                              const int* __restrict__ deg, float* __restrict__ hidden, int N) {
  __shared__ float At[32][68];   // [k][node], stride 68 keeps b128 alignment
  __shared__ float Was[32][64];  // [k][out]
  __shared__ float Wbs[32][64];
  int tid = threadIdx.x;        // 0..127
  int tx = tid & 15;            // out group: outs tx*4..tx*4+3
  int tn = tid >> 4;            // node group: nodes tn*8..tn*8+7 (0..7)
  int n0 = blockIdx.x * 64;
  float acc_a[8][4] = {{0.f}}, acc_b[8][4] = {{0.f}};
  // A staging: thread -> node = tid>>1 (0..63), k-half = (tid&1)*16 (16 floats = 4 x float4)
  int anode = tid >> 1;
  int akh = (tid & 1) * 16;
  bool avalid = (n0 + anode) < N;
  const float* Arow = f1 + (size_t)(n0 + anode) * 256 + akh;
  const float4* WaG = (const float4*)(aggW);
  const float4* WbG = (const float4*)(aggW + (size_t)256 * 64);

  for (int kc = 0; kc < 8; ++kc) {
    float4 v[4];
    if (avalid) {
      const float4* ap = (const float4*)(Arow + kc * 32);
      #pragma unroll
      for (int s = 0; s < 4; ++s) v[s] = ap[s];
    } else {
      #pragma unroll
      for (int s = 0; s < 4; ++s) v[s] = make_float4(0.f, 0.f, 0.f, 0.f);
    }
    #pragma unroll
    for (int s = 0; s < 4; ++s) {
      At[akh + s * 4 + 0][anode] = v[s].x; At[akh + s * 4 + 1][anode] = v[s].y;
      At[akh + s * 4 + 2][anode] = v[s].z; At[akh + s * 4 + 3][anode] = v[s].w;
    }
    #pragma unroll
    for (int i = 0; i < 4; ++i) {
      ((float4*)Was)[tid + i * 128] = WaG[kc * 512 + tid + i * 128];
      ((float4*)Wbs)[tid + i * 128] = WbG[kc * 512 + tid + i * 128];
    }
    __syncthreads();
    #pragma unroll 4
    for (int kk = 0; kk < 32; ++kk) {
      float4 a0 = *(const float4*)&At[kk][tn * 8];
      float4 a1 = *(const float4*)&At[kk][tn * 8 + 4];
      float4 wa = *(const float4*)&Was[kk][tx * 4];
      float4 wb = *(const float4*)&Wbs[kk][tx * 4];
      float an[8] = {a0.x, a0.y, a0.z, a0.w, a1.x, a1.y, a1.z, a1.w};
      #pragma unroll
      for (int i = 0; i < 8; ++i) {
        acc_a[i][0] += an[i] * wa.x; acc_a[i][1] += an[i] * wa.y;
        acc_a[i][2] += an[i] * wa.z; acc_a[i][3] += an[i] * wa.w;
        acc_b[i][0] += an[i] * wb.x; acc_b[i][1] += an[i] * wb.y;
        acc_b[i][2] += an[i] * wb.z; acc_b[i][3] += an[i] * wb.w;
      }
    }
    __syncthreads();
  }

  float4 bj = *(const float4*)(aggb + tx * 4);
  #pragma unroll
  for (int i = 0; i < 8; ++i) {
    int node = n0 + tn * 8 + i;
    if (node < N && deg[node] > 0) {
      float sc = scale[node];
      float4* hp = (float4*)(hidden + (size_t)node * 64 + tx * 4);
      float4 h = *hp;
      h.x += acc_a[i][0] + sc * acc_b[i][0] + bj.x;
      h.y += acc_a[i][1] + sc * acc_b[i][1] + bj.y;
      h.z += acc_a[i][2] + sc * acc_b[i][2] + bj.z;
      h.w += acc_a[i][3] + sc * acc_b[i][3] + bj.w;
      *hp = h;
    }
  }
}

// ---------------- score: register-blocked tile kernel ----------------
// 64 nodes per block, 256 threads. lane = node (0..63), g = tid>>6 (0..3).
// Phase A: heur = H @ lin_W[0:64] + cq, x = H * heur (16 indep acc/thread).
// Phase B: h1 = relu(x @ W1 + b1), p = sum(h1 * W2) (32 indep acc/thread).
// LDS layout (floats), phase-overlapped:
//   X  @ 0     (64*65 = 4160)
//   H  @ 4160  (4160)           } phase A
//   WA @ 8320  (4096)           } phase A (lin_W rows 0..63)
//   W1 @ 4160  (8192)           } phase B (overwrites H+WA after sync)
//   sW2 @ 12416 (128), sb1 @ 12544 (128), scq @ 12672 (64), pred @ 12736 (256)
#define SC_LDS 12992
__global__ __launch_bounds__(256) void score2_k(const float* __restrict__ hidden, float* __restrict__ score,
                                                const int* __restrict__ deg, const float* __restrict__ lin_W,
                                                const float* __restrict__ mlp_W1, const float* __restrict__ mlp_b1,
                                                const float* __restrict__ mlp_W2, const float* __restrict__ mlp_b2,
                                                const float* __restrict__ scalars, int N) {
  __shared__ float smem[SC_LDS];
  float* X   = smem;
  float* H   = smem + 4160;
  float* WA  = smem + 8320;
  float* W1s = smem + 4160;
  float* sW2 = smem + 12416;
  float* sb1 = smem + 12544;
  float* scq = smem + 12672;
  float* pred= smem + 12736;

  int t = threadIdx.x;
  int lane = t & 63;        // node within tile
  int g = t >> 6;           // 0..3
  int n0 = blockIdx.x * 64;

  // stage lin_W rows 0..63 (hidden part), smalls
  for (int i = t; i < 1024; i += 256) ((float4*)WA)[i] = ((const float4*)lin_W)[i];
  if (t < 128) { sW2[t] = mlp_W2[t]; sb1[t] = mlp_b1[t]; }
  if (t < 64) scq[t] = scalars[t];
  // stage hidden tile -> H[node][k] with stride 65
  for (int i = t; i < 1024; i += 256) {
    int node = i >> 4;
    int k4 = (i & 15) << 2;
    float4 v = make_float4(0.f, 0.f, 0.f, 0.f);
    if (n0 + node < N) v = ((const float4*)(hidden + (size_t)(n0 + node) * 64))[i & 15];
    float* hp = &H[node * 65 + k4];
    hp[0] = v.x; hp[1] = v.y; hp[2] = v.z; hp[3] = v.w;
  }
  __syncthreads();

  // Phase A: heur (16 outputs j = g*16 + i per thread, node = lane)
  float acc[16];
  #pragma unroll
  for (int i = 0; i < 16; ++i) acc[i] = scq[g * 16 + i];
  #pragma unroll 8
  for (int kk = 0; kk < 64; ++kk) {
    float h = H[lane * 65 + kk];                       // 2-way alias: free
    const float4* wr = (const float4*)&WA[kk * 64 + g * 16];  // broadcast
    float4 w0 = wr[0], w1 = wr[1], w2 = wr[2], w3 = wr[3];
    acc[0]  += h * w0.x; acc[1]  += h * w0.y; acc[2]  += h * w0.z; acc[3]  += h * w0.w;
    acc[4]  += h * w1.x; acc[5]  += h * w1.y; acc[6]  += h * w1.z; acc[7]  += h * w1.w;
    acc[8]  += h * w2.x; acc[9]  += h * w2.y; acc[10] += h * w2.z; acc[11] += h * w2.w;
    acc[12] += h * w3.x; acc[13] += h * w3.y; acc[14] += h * w3.z; acc[15] += h * w3.w;
  }
  // x = H * heur, store to X
  #pragma unroll
  for (int i = 0; i < 16; ++i) {
    int j = g * 16 + i;
    X[lane * 65 + j] = H[lane * 65 + j] * acc[i];
  }
  __syncthreads();  // X complete; H/WA now dead

  // stage W1 (64x128) into the H/WA region
  for (int i = t; i < 2048; i += 256) ((float4*)W1s)[i] = ((const float4*)mlp_W1)[i];
  __syncthreads();

  // Phase B: h1 j2 = g*32 + i, node = lane
  float acc2[32];
  #pragma unroll
  for (int i = 0; i < 32; ++i) acc2[i] = sb1[g * 32 + i];
  #pragma unroll 4
  for (int kk = 0; kk < 64; ++kk) {
    float xv = X[lane * 65 + kk];
    const float4* wr = (const float4*)&W1s[kk * 128 + g * 32];  // broadcast
    #pragma unroll
    for (int s = 0; s < 8; ++s) {
      float4 w = wr[s];
      acc2[s * 4 + 0] += xv * w.x; acc2[s * 4 + 1] += xv * w.y;
      acc2[s * 4 + 2] += xv * w.z; acc2[s * 4 + 3] += xv * w.w;
    }
  }
  float p = 0.f;
  #pragma unroll
  for (int i = 0; i < 32; ++i) p += fmaxf(acc2[i], 0.f) * sW2[g * 32 + i];
  pred[g * 64 + lane] = p;
  __syncthreads();
  if (t < 64) {
    int node = n0 + t;
    if (node < N && deg[node] > 0)
      score[node] = pred[t] + pred[64 + t] + pred[128 + t] + pred[192 + t] + mlp_b2[0];
  }
}

__global__ void out_k(const float* __restrict__ score, const int* __restrict__ t_index,
                      float* __restrict__ out, int T) {
  int i = blockIdx.x * blockDim.x + threadIdx.x;
  if (i < T) out[i] = score[t_index[i]];
}

// ---------------- launch ----------------
extern "C" void kernel_launch(void* const* d_in, const int* in_sizes, int n_in,
                              void* d_out, int out_size, void* d_ws, size_t ws_size,
                              hipStream_t stream) {
  const float* head_embeds = (const float*)d_in[0];
  const float* rel_table   = (const float*)d_in[1];
  const float* rel_W       = (const float*)d_in[2];
  const float* agg_W       = (const float*)d_in[3];
  const float* agg_b       = (const float*)d_in[4];
  const float* lin_W       = (const float*)d_in[5];
  const float* lin_b       = (const float*)d_in[6];
  const float* mlp_W1      = (const float*)d_in[7];
  const float* mlp_b1      = (const float*)d_in[8];
  const float* mlp_W2      = (const float*)d_in[9];
  const float* mlp_b2      = (const float*)d_in[10];
  const int* edge_src      = (const int*)d_in[11];
  const int* edge_dst      = (const int*)d_in[12];
  const int* edge_type     = (const int*)d_in[13];
  const int* head_index    = (const int*)d_in[14];
  const int* r_index       = (const int*)d_in[15];
  const int* t_index       = (const int*)d_in[16];
  int E = in_sizes[11];
  int T = in_sizes[16];
  int N = NN;

  char* w = (char*)d_ws;
  size_t off = 0;
  auto alloc = [&](size_t bytes) {
    void* p = w + off;
    off = (off + bytes + 255) & ~(size_t)255;
    return p;
  };
  int* deg      = (int*)alloc((size_t)N * 4);
  int* start    = (int*)alloc((size_t)N * 4);
  int* cursor   = (int*)alloc((size_t)N * 4);
  float* scale  = (float*)alloc((size_t)N * 4);
  int* counter  = (int*)alloc(4);
  float* logsum = (float*)alloc(4);
  float* scalars= (float*)alloc(66 * 4);
  int2* csr     = (int2*)alloc((size_t)E * 8);
  float* hidden = (float*)alloc((size_t)N * 64 * 4);
  float* score  = (float*)alloc((size_t)N * 4);
  float* f1     = (float*)alloc((size_t)N * 256 * 4);
  if (off > ws_size) return;  // workspace too small -> fail loudly via wrong output

  hipMemsetAsync(deg, 0, (size_t)N * 4, stream);
  hipMemsetAsync(counter, 0, 4, stream);
  hipMemsetAsync(logsum, 0, 4, stream);
  hipMemsetAsync(hidden, 0, (size_t)N * 64 * 4, stream);

  count_k<<<(E + 255) / 256, 256, 0, stream>>>(edge_dst, deg, E);
  scan_k<<<(N + 255) / 256, 256, 0, stream>>>(deg, start, cursor, counter, logsum, N);
  scale_k<<<(N + 255) / 256, 256, 0, stream>>>(deg, logsum, scale, N);
  scatter_k<<<(E + 255) / 256, 256, 0, stream>>>(edge_src, edge_dst, edge_type, cursor, csr, E);
  prep_k<<<1, 64, 0, stream>>>(head_embeds, rel_table, lin_W, lin_b, mlp_W1, mlp_b1, mlp_W2, mlp_b2,
                               head_index, r_index, hidden, scalars);
  fill_k<<<(N + 255) / 256, 256, 0, stream>>>(score, scalars, head_index, N);

  for (int l = 0; l < NLAYERS; ++l) {
    agg_k<<<(N + 3) / 4, 256, 0, stream>>>(hidden, score, csr, start, deg,
                                           rel_W + (size_t)l * NREL * 64, f1, N);
    gemm_k<<<(N + 63) / 64, 128, 0, stream>>>(f1, agg_W + (size_t)l * 512 * 64, agg_b + (size_t)l * 64,
                                              scale, deg, hidden, N);
    score2_k<<<(N + 63) / 64, 256, 0, stream>>>(hidden, score, deg, lin_W, mlp_W1, mlp_b1, mlp_W2, mlp_b2,
                                                scalars, N);
  }
  out_k<<<(T + 255) / 256, 256, 0, stream>>>(score, t_index, (float*)d_out, T);
}

// Round 12
// 586.225 us; speedup vs baseline: 1.1280x; 1.1280x over previous
//
#include <hip/hip_runtime.h>
#include <math.h>

#define NN 50000
#define NREL 400
#define NLAYERS 3

static __device__ __forceinline__ float clip15(float x) { return fminf(fmaxf(x, -15.f), 15.f); }

// ---------------- CSR build ----------------
__global__ void count_k(const int* __restrict__ dst, int* __restrict__ deg, int E) {
  int e = blockIdx.x * blockDim.x + threadIdx.x;
  if (e < E) atomicAdd(&deg[dst[e]], 1);
}

__global__ void scan_k(const int* __restrict__ deg, int* __restrict__ start, int* __restrict__ cursor,
                       int* __restrict__ counter, float* __restrict__ logsum, int N) {
  int n = blockIdx.x * blockDim.x + threadIdx.x;
  int lane = threadIdx.x & 63;
  int d = (n < N) ? deg[n] : 0;
  int pre = d;
  #pragma unroll
  for (int off = 1; off < 64; off <<= 1) { int t = __shfl_up(pre, off); if (lane >= off) pre += t; }
  int base = 0;
  if (lane == 63) base = atomicAdd(counter, pre);
  base = __shfl(base, 63);
  if (n < N) { int pos = base + pre - d; start[n] = pos; cursor[n] = pos; }
  float v = (n < N) ? logf((float)d + 1.0f) : 0.f;
  #pragma unroll
  for (int off = 32; off; off >>= 1) v += __shfl_xor(v, off);
  if (lane == 0) atomicAdd(logsum, v);
}

__global__ void scale_k(const int* __restrict__ deg, const float* __restrict__ logsum,
                        float* __restrict__ scale, int N) {
  int n = blockIdx.x * blockDim.x + threadIdx.x;
  if (n < N) scale[n] = logf((float)deg[n] + 1.0f) * (float)N / logsum[0];
}

__global__ void scatter_k(const int* __restrict__ src, const int* __restrict__ dst,
                          const int* __restrict__ typ, int* __restrict__ cursor,
                          int2* __restrict__ csr, int E) {
  int e = blockIdx.x * blockDim.x + threadIdx.x;
  if (e < E) {
    int dd = dst[e];
    int pos = atomicAdd(&cursor[dd], 1);
    csr[pos] = make_int2(src[e], typ[e]);
  }
}

// ---------------- init ----------------
// scalars layout: [0..63]=c_q (lin_b + q @ lin_W[64:128]) ; [64]=zero_s ; [65]=head_s
__global__ void prep_k(const float* __restrict__ head_embeds, const float* __restrict__ rel_table,
                       const float* __restrict__ lin_W, const float* __restrict__ lin_b,
                       const float* __restrict__ mlp_W1, const float* __restrict__ mlp_b1,
                       const float* __restrict__ mlp_W2, const float* __restrict__ mlp_b2,
                       const int* __restrict__ head_index, const int* __restrict__ r_index,
                       float* __restrict__ hidden, float* __restrict__ scalars) {
  int j = threadIdx.x;  // 0..63
  int r = r_index[0], hd = head_index[0];
  float qj = rel_table[r * 64 + j];
  float cq = lin_b[j];
  for (int k = 0; k < 64; ++k) cq += __shfl(qj, k) * lin_W[(64 + k) * 64 + j];
  scalars[j] = cq;
  // zero score: x = 0 -> h1 = relu(b1)
  float t = fmaxf(mlp_b1[j], 0.f) * mlp_W2[j] + fmaxf(mlp_b1[64 + j], 0.f) * mlp_W2[64 + j];
  #pragma unroll
  for (int off = 32; off; off >>= 1) t += __shfl_xor(t, off);
  float zs = clip15(t + mlp_b2[0]);
  // head node
  float hj = head_embeds[j];
  hidden[(size_t)hd * 64 + j] = hj;
  float heur = cq;
  for (int k = 0; k < 64; ++k) heur += __shfl(hj, k) * lin_W[k * 64 + j];
  float xj = hj * heur;
  float h1a = mlp_b1[j], h1b = mlp_b1[64 + j];
  for (int k = 0; k < 64; ++k) {
    float xk = __shfl(xj, k);
    h1a += xk * mlp_W1[k * 128 + j];
    h1b += xk * mlp_W1[k * 128 + 64 + j];
  }
  h1a = fmaxf(h1a, 0.f); h1b = fmaxf(h1b, 0.f);
  float p = h1a * mlp_W2[j] + h1b * mlp_W2[64 + j];
  #pragma unroll
  for (int off = 32; off; off >>= 1) p += __shfl_xor(p, off);
  float hs = clip15(p + mlp_b2[0]);
  if (j == 0) { scalars[64] = zs; scalars[65] = hs; }
}

__global__ void fill_k(float* __restrict__ score, const float* __restrict__ scalars,
                       const int* __restrict__ head_index, int N) {
  int n = blockIdx.x * blockDim.x + threadIdx.x;
  if (n < N) score[n] = (n == head_index[0]) ? scalars[65] : scalars[64];
}

// ---------------- per-layer ----------------
__global__ void gate_k(const float* __restrict__ hidden, const float* __restrict__ score,
                       float* __restrict__ LI, int N) {
  int i = blockIdx.x * blockDim.x + threadIdx.x;
  if (i < N * 16) {
    int node = i >> 4;
    float s = score[node];
    float g = 1.f / (1.f + expf(-s));
    float4 h = ((const float4*)hidden)[i];
    float4 r = make_float4(h.x * g, h.y * g, h.z * g, h.w * g);
    ((float4*)LI)[i] = r;
  }
}

// one wave per node; lane = dim; 8-wide edge unroll (deg ~ Poisson(16) -> ~2 full iters)
__global__ __launch_bounds__(256) void agg_k(const float* __restrict__ LI, const int2* __restrict__ csr,
                                             const int* __restrict__ start, const int* __restrict__ deg,
                                             const float* __restrict__ relW, float* __restrict__ f1, int N) {
  int wid = threadIdx.x >> 6;
  int lane = threadIdx.x & 63;
  int node = blockIdx.x * 4 + wid;
  if (node >= N) return;
  int base = start[node], d = deg[node];
  float sum = 0.f, sq = 0.f, mx = -3.402823e38f, mn = 3.402823e38f;
  int e = 0;
  for (; e + 8 <= d; e += 8) {
    int2 p[8];
    #pragma unroll
    for (int i = 0; i < 8; ++i) p[i] = csr[base + e + i];
    float m[8];
    #pragma unroll
    for (int i = 0; i < 8; ++i) {
      float a = LI[p[i].x * 64 + lane];
      float w = relW[p[i].y * 64 + lane];
      m[i] = a * w;
    }
    #pragma unroll
    for (int i = 0; i < 8; ++i) {
      sum += m[i]; sq += m[i] * m[i];
      mx = fmaxf(mx, m[i]); mn = fminf(mn, m[i]);
    }
  }
  for (; e + 4 <= d; e += 4) {
    int2 p0 = csr[base + e], p1 = csr[base + e + 1];
    int2 p2 = csr[base + e + 2], p3 = csr[base + e + 3];
    float a0 = LI[p0.x * 64 + lane], w0 = relW[p0.y * 64 + lane];
    float a1 = LI[p1.x * 64 + lane], w1 = relW[p1.y * 64 + lane];
    float a2 = LI[p2.x * 64 + lane], w2 = relW[p2.y * 64 + lane];
    float a3 = LI[p3.x * 64 + lane], w3 = relW[p3.y * 64 + lane];
    float m0 = a0 * w0, m1 = a1 * w1, m2 = a2 * w2, m3 = a3 * w3;
    sum += (m0 + m1) + (m2 + m3);
    sq += (m0 * m0 + m1 * m1) + (m2 * m2 + m3 * m3);
    mx = fmaxf(fmaxf(mx, fmaxf(m0, m1)), fmaxf(m2, m3));
    mn = fminf(fminf(mn, fminf(m0, m1)), fminf(m2, m3));
  }
  for (; e < d; ++e) {
    int2 p = csr[base + e];
    float m = LI[p.x * 64 + lane] * relW[p.y * 64 + lane];
    sum += m; sq += m * m; mx = fmaxf(mx, m); mn = fminf(mn, m);
  }
  float* out = f1 + (size_t)node * 256;
  if (d > 0) {
    float inv = 1.0f / (float)d;
    float mean = sum * inv, sqm = sq * inv;
    float sd = sqrtf(fmaxf(sqm - mean * mean, 0.f) + 1e-6f);
    out[lane] = mean; out[64 + lane] = mx; out[128 + lane] = mn; out[192 + lane] = sd;
  } else {
    out[lane] = 0.f; out[64 + lane] = 0.f; out[128 + lane] = 0.f; out[192 + lane] = 0.f;
  }
}

// update = f1 @ Wa + scale*(f1 @ Wb) + b ; hidden += update (deg>0)
// r6 best-measured config (62 us): 256 thr, 4n x 4o x {a,b} = 32 acc, single-buffer 25 KB.
// LDS-issue model: ~110k cyc/CU of ds_read vs ~150k kernel -> this structure's frontier;
// further gains need fewer operand bytes/FLOP (bf16/MFMA), not rebalancing (r10/r11 data).
__global__ __launch_bounds__(256) void gemm_k(const float* __restrict__ f1, const float* __restrict__ aggW,
                                              const float* __restrict__ aggb, const float* __restrict__ scale,
                                              const int* __restrict__ deg, float* __restrict__ hidden, int N) {
  __shared__ float At[32][68];   // [k][node], stride 68 keeps 16B alignment
  __shared__ float Was[32][64];
  __shared__ float Wbs[32][64];
  int tid = threadIdx.x;
  int tx = tid & 15;    // out group: outs tx*4..tx*4+3
  int tn = tid >> 4;    // node group: nodes tn*4..tn*4+3
  int n0 = blockIdx.x * 64;
  float acc_a[4][4] = {{0.f}}, acc_b[4][4] = {{0.f}};
  // A staging mapping: thread -> node = tid>>2 (0..63), k-offset = (tid&3)*8
  int anode = tid >> 2;
  int ak = (tid & 3) * 8;
  bool avalid = (n0 + anode) < N;
  const float* Arow = f1 + (size_t)(n0 + anode) * 256 + ak;
  const float4* WaG = (const float4*)(aggW);
  const float4* WbG = (const float4*)(aggW + (size_t)256 * 64);
  for (int kc = 0; kc < 8; ++kc) {
    float4 v0 = make_float4(0.f, 0.f, 0.f, 0.f), v1 = v0;
    if (avalid) {
      const float4* ap = (const float4*)(Arow + kc * 32);
      v0 = ap[0]; v1 = ap[1];
    }
    At[ak + 0][anode] = v0.x; At[ak + 1][anode] = v0.y;
    At[ak + 2][anode] = v0.z; At[ak + 3][anode] = v0.w;
    At[ak + 4][anode] = v1.x; At[ak + 5][anode] = v1.y;
    At[ak + 6][anode] = v1.z; At[ak + 7][anode] = v1.w;
    ((float4*)Was)[tid] = WaG[kc * 512 + tid];
    ((float4*)Was)[tid + 256] = WaG[kc * 512 + 256 + tid];
    ((float4*)Wbs)[tid] = WbG[kc * 512 + tid];
    ((float4*)Wbs)[tid + 256] = WbG[kc * 512 + 256 + tid];
    __syncthreads();
    #pragma unroll 8
    for (int kk = 0; kk < 32; ++kk) {
      float4 a  = *(const float4*)&At[kk][tn * 4];
      float4 wa = *(const float4*)&Was[kk][tx * 4];
      float4 wb = *(const float4*)&Wbs[kk][tx * 4];
      acc_a[0][0] += a.x * wa.x; acc_a[0][1] += a.x * wa.y; acc_a[0][2] += a.x * wa.z; acc_a[0][3] += a.x * wa.w;
      acc_a[1][0] += a.y * wa.x; acc_a[1][1] += a.y * wa.y; acc_a[1][2] += a.y * wa.z; acc_a[1][3] += a.y * wa.w;
      acc_a[2][0] += a.z * wa.x; acc_a[2][1] += a.z * wa.y; acc_a[2][2] += a.z * wa.z; acc_a[2][3] += a.z * wa.w;
      acc_a[3][0] += a.w * wa.x; acc_a[3][1] += a.w * wa.y; acc_a[3][2] += a.w * wa.z; acc_a[3][3] += a.w * wa.w;
      acc_b[0][0] += a.x * wb.x; acc_b[0][1] += a.x * wb.y; acc_b[0][2] += a.x * wb.z; acc_b[0][3] += a.x * wb.w;
      acc_b[1][0] += a.y * wb.x; acc_b[1][1] += a.y * wb.y; acc_b[1][2] += a.y * wb.z; acc_b[1][3] += a.y * wb.w;
      acc_b[2][0] += a.z * wb.x; acc_b[2][1] += a.z * wb.y; acc_b[2][2] += a.z * wb.z; acc_b[2][3] += a.z * wb.w;
      acc_b[3][0] += a.w * wb.x; acc_b[3][1] += a.w * wb.y; acc_b[3][2] += a.w * wb.z; acc_b[3][3] += a.w * wb.w;
    }
    __syncthreads();
  }
  float4 bj = *(const float4*)(aggb + tx * 4);
  #pragma unroll
  for (int i = 0; i < 4; ++i) {
    int node = n0 + tn * 4 + i;
    if (node < N && deg[node] > 0) {
      float sc = scale[node];
      float4* hp = (float4*)(hidden + (size_t)node * 64 + tx * 4);
      float4 h = *hp;
      h.x += acc_a[i][0] + sc * acc_b[i][0] + bj.x;
      h.y += acc_a[i][1] + sc * acc_b[i][1] + bj.y;
      h.z += acc_a[i][2] + sc * acc_b[i][2] + bj.z;
      h.w += acc_a[i][3] + sc * acc_b[i][3] + bj.w;
      *hp = h;
    }
  }
}

// ---------------- score: register-blocked tile kernel ----------------
#define SC_LDS 12992
__global__ __launch_bounds__(256) void score2_k(const float* __restrict__ hidden, float* __restrict__ score,
                                                const int* __restrict__ deg, const float* __restrict__ lin_W,
                                                const float* __restrict__ mlp_W1, const float* __restrict__ mlp_b1,
                                                const float* __restrict__ mlp_W2, const float* __restrict__ mlp_b2,
                                                const float* __restrict__ scalars, int N) {
  __shared__ float smem[SC_LDS];
  float* X   = smem;
  float* H   = smem + 4160;
  float* WA  = smem + 8320;
  float* W1s = smem + 4160;
  float* sW2 = smem + 12416;
  float* sb1 = smem + 12544;
  float* scq = smem + 12672;
  float* pred= smem + 12736;

  int t = threadIdx.x;
  int lane = t & 63;        // node within tile
  int g = t >> 6;           // 0..3
  int n0 = blockIdx.x * 64;

  for (int i = t; i < 1024; i += 256) ((float4*)WA)[i] = ((const float4*)lin_W)[i];
  if (t < 128) { sW2[t] = mlp_W2[t]; sb1[t] = mlp_b1[t]; }
  if (t < 64) scq[t] = scalars[t];
  for (int i = t; i < 1024; i += 256) {
    int node = i >> 4;
    int k4 = (i & 15) << 2;
    float4 v = make_float4(0.f, 0.f, 0.f, 0.f);
    if (n0 + node < N) v = ((const float4*)(hidden + (size_t)(n0 + node) * 64))[i & 15];
    float* hp = &H[node * 65 + k4];
    hp[0] = v.x; hp[1] = v.y; hp[2] = v.z; hp[3] = v.w;
  }
  __syncthreads();

  float acc[16];
  #pragma unroll
  for (int i = 0; i < 16; ++i) acc[i] = scq[g * 16 + i];
  #pragma unroll 8
  for (int kk = 0; kk < 64; ++kk) {
    float h = H[lane * 65 + kk];
    const float4* wr = (const float4*)&WA[kk * 64 + g * 16];
    float4 w0 = wr[0], w1 = wr[1], w2 = wr[2], w3 = wr[3];
    acc[0]  += h * w0.x; acc[1]  += h * w0.y; acc[2]  += h * w0.z; acc[3]  += h * w0.w;
    acc[4]  += h * w1.x; acc[5]  += h * w1.y; acc[6]  += h * w1.z; acc[7]  += h * w1.w;
    acc[8]  += h * w2.x; acc[9]  += h * w2.y; acc[10] += h * w2.z; acc[11] += h * w2.w;
    acc[12] += h * w3.x; acc[13] += h * w3.y; acc[14] += h * w3.z; acc[15] += h * w3.w;
  }
  #pragma unroll
  for (int i = 0; i < 16; ++i) {
    int j = g * 16 + i;
    X[lane * 65 + j] = H[lane * 65 + j] * acc[i];
  }
  __syncthreads();

  for (int i = t; i < 2048; i += 256) ((float4*)W1s)[i] = ((const float4*)mlp_W1)[i];
  __syncthreads();

  float acc2[32];
  #pragma unroll
  for (int i = 0; i < 32; ++i) acc2[i] = sb1[g * 32 + i];
  #pragma unroll 4
  for (int kk = 0; kk < 64; ++kk) {
    float xv = X[lane * 65 + kk];
    const float4* wr = (const float4*)&W1s[kk * 128 + g * 32];
    #pragma unroll
    for (int s = 0; s < 8; ++s) {
      float4 w = wr[s];
      acc2[s * 4 + 0] += xv * w.x; acc2[s * 4 + 1] += xv * w.y;
      acc2[s * 4 + 2] += xv * w.z; acc2[s * 4 + 3] += xv * w.w;
    }
  }
  float p = 0.f;
  #pragma unroll
  for (int i = 0; i < 32; ++i) p += fmaxf(acc2[i], 0.f) * sW2[g * 32 + i];
  pred[g * 64 + lane] = p;
  __syncthreads();
  if (t < 64) {
    int node = n0 + t;
    if (node < N && deg[node] > 0)
      score[node] = pred[t] + pred[64 + t] + pred[128 + t] + pred[192 + t] + mlp_b2[0];
  }
}

__global__ void out_k(const float* __restrict__ score, const int* __restrict__ t_index,
                      float* __restrict__ out, int T) {
  int i = blockIdx.x * blockDim.x + threadIdx.x;
  if (i < T) out[i] = score[t_index[i]];
}

// ---------------- launch ----------------
extern "C" void kernel_launch(void* const* d_in, const int* in_sizes, int n_in,
                              void* d_out, int out_size, void* d_ws, size_t ws_size,
                              hipStream_t stream) {
  const float* head_embeds = (const float*)d_in[0];
  const float* rel_table   = (const float*)d_in[1];
  const float* rel_W       = (const float*)d_in[2];
  const float* agg_W       = (const float*)d_in[3];
  const float* agg_b       = (const float*)d_in[4];
  const float* lin_W       = (const float*)d_in[5];
  const float* lin_b       = (const float*)d_in[6];
  const float* mlp_W1      = (const float*)d_in[7];
  const float* mlp_b1      = (const float*)d_in[8];
  const float* mlp_W2      = (const float*)d_in[9];
  const float* mlp_b2      = (const float*)d_in[10];
  const int* edge_src      = (const int*)d_in[11];
  const int* edge_dst      = (const int*)d_in[12];
  const int* edge_type     = (const int*)d_in[13];
  const int* head_index    = (const int*)d_in[14];
  const int* r_index       = (const int*)d_in[15];
  const int* t_index       = (const int*)d_in[16];
  int E = in_sizes[11];
  int T = in_sizes[16];
  int N = NN;

  char* w = (char*)d_ws;
  size_t off = 0;
  auto alloc = [&](size_t bytes) {
    void* p = w + off;
    off = (off + bytes + 255) & ~(size_t)255;
    return p;
  };
  int* deg      = (int*)alloc((size_t)N * 4);
  int* start    = (int*)alloc((size_t)N * 4);
  int* cursor   = (int*)alloc((size_t)N * 4);
  float* scale  = (float*)alloc((size_t)N * 4);
  int* counter  = (int*)alloc(4);
  float* logsum = (float*)alloc(4);
  float* scalars= (float*)alloc(66 * 4);
  int2* csr     = (int2*)alloc((size_t)E * 8);
  float* hidden = (float*)alloc((size_t)N * 64 * 4);
  float* score  = (float*)alloc((size_t)N * 4);
  float* LI     = (float*)alloc((size_t)N * 64 * 4);
  float* f1     = (float*)alloc((size_t)N * 256 * 4);
  if (off > ws_size) return;  // workspace too small -> fail loudly via wrong output

  hipMemsetAsync(deg, 0, (size_t)N * 4, stream);
  hipMemsetAsync(counter, 0, 4, stream);
  hipMemsetAsync(logsum, 0, 4, stream);
  hipMemsetAsync(hidden, 0, (size_t)N * 64 * 4, stream);

  count_k<<<(E + 255) / 256, 256, 0, stream>>>(edge_dst, deg, E);
  scan_k<<<(N + 255) / 256, 256, 0, stream>>>(deg, start, cursor, counter, logsum, N);
  scale_k<<<(N + 255) / 256, 256, 0, stream>>>(deg, logsum, scale, N);
  scatter_k<<<(E + 255) / 256, 256, 0, stream>>>(edge_src, edge_dst, edge_type, cursor, csr, E);
  prep_k<<<1, 64, 0, stream>>>(head_embeds, rel_table, lin_W, lin_b, mlp_W1, mlp_b1, mlp_W2, mlp_b2,
                               head_index, r_index, hidden, scalars);
  fill_k<<<(N + 255) / 256, 256, 0, stream>>>(score, scalars, head_index, N);

  for (int l = 0; l < NLAYERS; ++l) {
    gate_k<<<(N * 16 + 255) / 256, 256, 0, stream>>>(hidden, score, LI, N);
    agg_k<<<(N + 3) / 4, 256, 0, stream>>>(LI, csr, start, deg, rel_W + (size_t)l * NREL * 64, f1, N);
    gemm_k<<<(N + 63) / 64, 256, 0, stream>>>(f1, agg_W + (size_t)l * 512 * 64, agg_b + (size_t)l * 64,
                                              scale, deg, hidden, N);
    score2_k<<<(N + 63) / 64, 256, 0, stream>>>(hidden, score, deg, lin_W, mlp_W1, mlp_b1, mlp_W2, mlp_b2,
                                                scalars, N);
  }
  out_k<<<(T + 255) / 256, 256, 0, stream>>>(score, t_index, (float*)d_out, T);
}

// Round 13
// 504.150 us; speedup vs baseline: 1.3116x; 1.1628x over previous
//
#include <hip/hip_runtime.h>
#include <math.h>

#define NN 50000
#define NREL 400
#define NLAYERS 3

static __device__ __forceinline__ float clip15(float x) { return fminf(fmaxf(x, -15.f), 15.f); }

// bf16 RNE split helpers (bit-level, used identically in wconv_k and gemm_k staging)
static __device__ __forceinline__ unsigned short f2bf(float f) {
  unsigned u = __float_as_uint(f);
  unsigned r = (u + 0x7FFFu + ((u >> 16) & 1u)) >> 16;
  return (unsigned short)r;
}
static __device__ __forceinline__ float bf2f(unsigned short s) {
  return __uint_as_float(((unsigned)s) << 16);
}

typedef __attribute__((ext_vector_type(8))) short bf16x8;
typedef __attribute__((ext_vector_type(4))) float f32x4;

// ---------------- CSR build ----------------
__global__ void count_k(const int* __restrict__ dst, int* __restrict__ deg, int E) {
  int e = blockIdx.x * blockDim.x + threadIdx.x;
  if (e < E) atomicAdd(&deg[dst[e]], 1);
}

__global__ void scan_k(const int* __restrict__ deg, int* __restrict__ start, int* __restrict__ cursor,
                       int* __restrict__ counter, float* __restrict__ logsum, int N) {
  int n = blockIdx.x * blockDim.x + threadIdx.x;
  int lane = threadIdx.x & 63;
  int d = (n < N) ? deg[n] : 0;
  int pre = d;
  #pragma unroll
  for (int off = 1; off < 64; off <<= 1) { int t = __shfl_up(pre, off); if (lane >= off) pre += t; }
  int base = 0;
  if (lane == 63) base = atomicAdd(counter, pre);
  base = __shfl(base, 63);
  if (n < N) { int pos = base + pre - d; start[n] = pos; cursor[n] = pos; }
  float v = (n < N) ? logf((float)d + 1.0f) : 0.f;
  #pragma unroll
  for (int off = 32; off; off >>= 1) v += __shfl_xor(v, off);
  if (lane == 0) atomicAdd(logsum, v);
}

__global__ void scale_k(const int* __restrict__ deg, const float* __restrict__ logsum,
                        float* __restrict__ scale, int N) {
  int n = blockIdx.x * blockDim.x + threadIdx.x;
  if (n < N) scale[n] = logf((float)deg[n] + 1.0f) * (float)N / logsum[0];
}

__global__ void scatter_k(const int* __restrict__ src, const int* __restrict__ dst,
                          const int* __restrict__ typ, int* __restrict__ cursor,
                          int2* __restrict__ csr, int E) {
  int e = blockIdx.x * blockDim.x + threadIdx.x;
  if (e < E) {
    int dd = dst[e];
    int pos = atomicAdd(&cursor[dd], 1);
    csr[pos] = make_int2(src[e], typ[e]);
  }
}

// ---------------- W pre-convert: aggW [3][512][64] f32 -> WT [3][4][64][256] bf16 ----------------
// part 0 = Wa_hi, 1 = Wa_lo (k 0..255); 2 = Wb_hi, 3 = Wb_lo (k 256..511). Layout [out][k].
__global__ void wconv_k(const float* __restrict__ aggW, unsigned short* __restrict__ WT) {
  int idx = blockIdx.x * blockDim.x + threadIdx.x;   // over 3*64*256
  if (idx >= 3 * 64 * 256) return;
  int k = idx & 255;
  int out = (idx >> 8) & 63;
  int l = idx >> 14;
  const float* Wl = aggW + (size_t)l * 512 * 64;
  float wa = Wl[(size_t)k * 64 + out];
  float wb = Wl[(size_t)(256 + k) * 64 + out];
  unsigned short wah = f2bf(wa);
  unsigned short wal = f2bf(wa - bf2f(wah));
  unsigned short wbh = f2bf(wb);
  unsigned short wbl = f2bf(wb - bf2f(wbh));
  unsigned short* WTl = WT + (size_t)l * 4 * 64 * 256;
  WTl[((size_t)0 * 64 + out) * 256 + k] = wah;
  WTl[((size_t)1 * 64 + out) * 256 + k] = wal;
  WTl[((size_t)2 * 64 + out) * 256 + k] = wbh;
  WTl[((size_t)3 * 64 + out) * 256 + k] = wbl;
}

// ---------------- init ----------------
// scalars layout: [0..63]=c_q (lin_b + q @ lin_W[64:128]) ; [64]=zero_s ; [65]=head_s
__global__ void prep_k(const float* __restrict__ head_embeds, const float* __restrict__ rel_table,
                       const float* __restrict__ lin_W, const float* __restrict__ lin_b,
                       const float* __restrict__ mlp_W1, const float* __restrict__ mlp_b1,
                       const float* __restrict__ mlp_W2, const float* __restrict__ mlp_b2,
                       const int* __restrict__ head_index, const int* __restrict__ r_index,
                       float* __restrict__ hidden, float* __restrict__ scalars) {
  int j = threadIdx.x;  // 0..63
  int r = r_index[0], hd = head_index[0];
  float qj = rel_table[r * 64 + j];
  float cq = lin_b[j];
  for (int k = 0; k < 64; ++k) cq += __shfl(qj, k) * lin_W[(64 + k) * 64 + j];
  scalars[j] = cq;
  float t = fmaxf(mlp_b1[j], 0.f) * mlp_W2[j] + fmaxf(mlp_b1[64 + j], 0.f) * mlp_W2[64 + j];
  #pragma unroll
  for (int off = 32; off; off >>= 1) t += __shfl_xor(t, off);
  float zs = clip15(t + mlp_b2[0]);
  float hj = head_embeds[j];
  hidden[(size_t)hd * 64 + j] = hj;
  float heur = cq;
  for (int k = 0; k < 64; ++k) heur += __shfl(hj, k) * lin_W[k * 64 + j];
  float xj = hj * heur;
  float h1a = mlp_b1[j], h1b = mlp_b1[64 + j];
  for (int k = 0; k < 64; ++k) {
    float xk = __shfl(xj, k);
    h1a += xk * mlp_W1[k * 128 + j];
    h1b += xk * mlp_W1[k * 128 + 64 + j];
  }
  h1a = fmaxf(h1a, 0.f); h1b = fmaxf(h1b, 0.f);
  float p = h1a * mlp_W2[j] + h1b * mlp_W2[64 + j];
  #pragma unroll
  for (int off = 32; off; off >>= 1) p += __shfl_xor(p, off);
  float hs = clip15(p + mlp_b2[0]);
  if (j == 0) { scalars[64] = zs; scalars[65] = hs; }
}

__global__ void fill_k(float* __restrict__ score, const float* __restrict__ scalars,
                       const int* __restrict__ head_index, int N) {
  int n = blockIdx.x * blockDim.x + threadIdx.x;
  if (n < N) score[n] = (n == head_index[0]) ? scalars[65] : scalars[64];
}

// ---------------- per-layer ----------------
__global__ void gate_k(const float* __restrict__ hidden, const float* __restrict__ score,
                       float* __restrict__ LI, int N) {
  int i = blockIdx.x * blockDim.x + threadIdx.x;
  if (i < N * 16) {
    int node = i >> 4;
    float s = score[node];
    float g = 1.f / (1.f + expf(-s));
    float4 h = ((const float4*)hidden)[i];
    float4 r = make_float4(h.x * g, h.y * g, h.z * g, h.w * g);
    ((float4*)LI)[i] = r;
  }
}

// one wave per node; lane = dim; 8-wide edge unroll
__global__ __launch_bounds__(256) void agg_k(const float* __restrict__ LI, const int2* __restrict__ csr,
                                             const int* __restrict__ start, const int* __restrict__ deg,
                                             const float* __restrict__ relW, float* __restrict__ f1, int N) {
  int wid = threadIdx.x >> 6;
  int lane = threadIdx.x & 63;
  int node = blockIdx.x * 4 + wid;
  if (node >= N) return;
  int base = start[node], d = deg[node];
  float sum = 0.f, sq = 0.f, mx = -3.402823e38f, mn = 3.402823e38f;
  int e = 0;
  for (; e + 8 <= d; e += 8) {
    int2 p[8];
    #pragma unroll
    for (int i = 0; i < 8; ++i) p[i] = csr[base + e + i];
    float m[8];
    #pragma unroll
    for (int i = 0; i < 8; ++i) {
      float a = LI[p[i].x * 64 + lane];
      float w = relW[p[i].y * 64 + lane];
      m[i] = a * w;
    }
    #pragma unroll
    for (int i = 0; i < 8; ++i) {
      sum += m[i]; sq += m[i] * m[i];
      mx = fmaxf(mx, m[i]); mn = fminf(mn, m[i]);
    }
  }
  for (; e + 4 <= d; e += 4) {
    int2 p0 = csr[base + e], p1 = csr[base + e + 1];
    int2 p2 = csr[base + e + 2], p3 = csr[base + e + 3];
    float a0 = LI[p0.x * 64 + lane], w0 = relW[p0.y * 64 + lane];
    float a1 = LI[p1.x * 64 + lane], w1 = relW[p1.y * 64 + lane];
    float a2 = LI[p2.x * 64 + lane], w2 = relW[p2.y * 64 + lane];
    float a3 = LI[p3.x * 64 + lane], w3 = relW[p3.y * 64 + lane];
    float m0 = a0 * w0, m1 = a1 * w1, m2 = a2 * w2, m3 = a3 * w3;
    sum += (m0 + m1) + (m2 + m3);
    sq += (m0 * m0 + m1 * m1) + (m2 * m2 + m3 * m3);
    mx = fmaxf(fmaxf(mx, fmaxf(m0, m1)), fmaxf(m2, m3));
    mn = fminf(fminf(mn, fminf(m0, m1)), fminf(m2, m3));
  }
  for (; e < d; ++e) {
    int2 p = csr[base + e];
    float m = LI[p.x * 64 + lane] * relW[p.y * 64 + lane];
    sum += m; sq += m * m; mx = fmaxf(mx, m); mn = fminf(mn, m);
  }
  float* out = f1 + (size_t)node * 256;
  if (d > 0) {
    float inv = 1.0f / (float)d;
    float mean = sum * inv, sqm = sq * inv;
    float sd = sqrtf(fmaxf(sqm - mean * mean, 0.f) + 1e-6f);
    out[lane] = mean; out[64 + lane] = mx; out[128 + lane] = mn; out[192 + lane] = sd;
  } else {
    out[lane] = 0.f; out[64 + lane] = 0.f; out[128 + lane] = 0.f; out[192 + lane] = 0.f;
  }
}

// update = f1 @ Wa + scale*(f1 @ Wb) + b ; hidden += update (deg>0)
// MFMA bf16-split (r12 theory: fp32 path is LDS-bytes-per-FLOP bound at ~62 us).
// a*w = a_hi*w_hi + a_hi*w_lo + a_lo*w_hi (3x mfma_f32_16x16x32_bf16, fp32 acc).
// Block: 64 nodes x (64 outs x {Wa,Wb}); 4 waves, wave = 16-node stripe, 8 C-tiles/wave.
// K chunked by 32 (one MFMA K-step); KP=40 pad -> uniform bank classes, conflict-free.
// LDS 30 KB -> 5 blocks/CU cap (grid-limited ~3). W pre-split/transposed by wconv_k.
#define KP 40
__global__ __launch_bounds__(256) void gemm_k(const float* __restrict__ f1,
                                              const unsigned short* __restrict__ WT,
                                              const float* __restrict__ aggb, const float* __restrict__ scale,
                                              const int* __restrict__ deg, float* __restrict__ hidden, int N) {
  __shared__ __align__(16) unsigned short sA[2][64 * KP];  // hi, lo
  __shared__ __align__(16) unsigned short sW[4][64 * KP];  // Wa_hi, Wa_lo, Wb_hi, Wb_lo
  int tid = threadIdx.x;
  int wv = tid >> 6;        // wave -> node stripe (16 rows)
  int l = tid & 63;
  int lrow = l & 15;
  int lhi = l >> 4;         // 0..3
  int n0 = blockIdx.x * 64;

  f32x4 acc[8];
  #pragma unroll
  for (int i = 0; i < 8; ++i) acc[i] = (f32x4){0.f, 0.f, 0.f, 0.f};

  // staging maps
  int anode = tid >> 2;            // 0..63
  int akq = (tid & 3) * 8;         // k offset within chunk (8 floats)
  bool avalid = (n0 + anode) < N;
  const float* Arow = f1 + (size_t)(n0 + anode) * 256 + akq;

  for (int kc = 0; kc < 8; ++kc) {
    // ---- stage A chunk (64 nodes x 32 k) as hi/lo bf16 ----
    float fv[8];
    if (avalid) {
      float4 v0 = *(const float4*)(Arow + kc * 32);
      float4 v1 = *(const float4*)(Arow + kc * 32 + 4);
      fv[0] = v0.x; fv[1] = v0.y; fv[2] = v0.z; fv[3] = v0.w;
      fv[4] = v1.x; fv[5] = v1.y; fv[6] = v1.z; fv[7] = v1.w;
    } else {
      #pragma unroll
      for (int j = 0; j < 8; ++j) fv[j] = 0.f;
    }
    unsigned int ph[4], pl[4];
    #pragma unroll
    for (int j = 0; j < 4; ++j) {
      unsigned short h0 = f2bf(fv[2 * j]),     l0 = f2bf(fv[2 * j] - bf2f(h0));
      unsigned short h1 = f2bf(fv[2 * j + 1]), l1 = f2bf(fv[2 * j + 1] - bf2f(h1));
      ph[j] = (unsigned)h0 | ((unsigned)h1 << 16);
      pl[j] = (unsigned)l0 | ((unsigned)l1 << 16);
    }
    *(uint4*)&sA[0][anode * KP + akq] = make_uint4(ph[0], ph[1], ph[2], ph[3]);
    *(uint4*)&sA[1][anode * KP + akq] = make_uint4(pl[0], pl[1], pl[2], pl[3]);
    // ---- stage W chunk: 4 parts x 64 out x 32 k ----
    {
      int wrow = tid >> 2;
      int wkq = (tid & 3) * 8;
      #pragma unroll
      for (int p = 0; p < 4; ++p) {
        const unsigned short* src = WT + ((size_t)p * 64 + wrow) * 256 + kc * 32 + wkq;
        *(uint4*)&sW[p][wrow * KP + wkq] = *(const uint4*)src;
      }
    }
    __syncthreads();
    // ---- compute: one K=32 MFMA step ----
    {
      int arow = (wv * 16 + lrow) * KP + lhi * 8;
      bf16x8 ah = *(const bf16x8*)&sA[0][arow];
      bf16x8 al = *(const bf16x8*)&sA[1][arow];
      #pragma unroll
      for (int t = 0; t < 4; ++t) {
        int wr = (t * 16 + lrow) * KP + lhi * 8;
        bf16x8 wah = *(const bf16x8*)&sW[0][wr];
        bf16x8 wal = *(const bf16x8*)&sW[1][wr];
        acc[t] = __builtin_amdgcn_mfma_f32_16x16x32_bf16(ah, wah, acc[t], 0, 0, 0);
        acc[t] = __builtin_amdgcn_mfma_f32_16x16x32_bf16(ah, wal, acc[t], 0, 0, 0);
        acc[t] = __builtin_amdgcn_mfma_f32_16x16x32_bf16(al, wah, acc[t], 0, 0, 0);
        bf16x8 wbh = *(const bf16x8*)&sW[2][wr];
        bf16x8 wbl = *(const bf16x8*)&sW[3][wr];
        acc[4 + t] = __builtin_amdgcn_mfma_f32_16x16x32_bf16(ah, wbh, acc[4 + t], 0, 0, 0);
        acc[4 + t] = __builtin_amdgcn_mfma_f32_16x16x32_bf16(ah, wbl, acc[4 + t], 0, 0, 0);
        acc[4 + t] = __builtin_amdgcn_mfma_f32_16x16x32_bf16(al, wbh, acc[4 + t], 0, 0, 0);
      }
    }
    __syncthreads();
  }

  // epilogue: C/D layout col=lane&15, row=(lane>>4)*4+reg  [m89 verified]
  #pragma unroll
  for (int r = 0; r < 4; ++r) {
    int node = n0 + wv * 16 + lhi * 4 + r;
    if (node < N && deg[node] > 0) {
      float sc = scale[node];
      #pragma unroll
      for (int t = 0; t < 4; ++t) {
        int out = t * 16 + lrow;
        float* hp = &hidden[(size_t)node * 64 + out];
        *hp += acc[t][r] + sc * acc[4 + t][r] + aggb[out];
      }
    }
  }
}

// ---------------- score: register-blocked tile kernel ----------------
#define SC_LDS 12992
__global__ __launch_bounds__(256) void score2_k(const float* __restrict__ hidden, float* __restrict__ score,
                                                const int* __restrict__ deg, const float* __restrict__ lin_W,
                                                const float* __restrict__ mlp_W1, const float* __restrict__ mlp_b1,
                                                const float* __restrict__ mlp_W2, const float* __restrict__ mlp_b2,
                                                const float* __restrict__ scalars, int N) {
  __shared__ float smem[SC_LDS];
  float* X   = smem;
  float* H   = smem + 4160;
  float* WA  = smem + 8320;
  float* W1s = smem + 4160;
  float* sW2 = smem + 12416;
  float* sb1 = smem + 12544;
  float* scq = smem + 12672;
  float* pred= smem + 12736;

  int t = threadIdx.x;
  int lane = t & 63;
  int g = t >> 6;
  int n0 = blockIdx.x * 64;

  for (int i = t; i < 1024; i += 256) ((float4*)WA)[i] = ((const float4*)lin_W)[i];
  if (t < 128) { sW2[t] = mlp_W2[t]; sb1[t] = mlp_b1[t]; }
  if (t < 64) scq[t] = scalars[t];
  for (int i = t; i < 1024; i += 256) {
    int node = i >> 4;
    int k4 = (i & 15) << 2;
    float4 v = make_float4(0.f, 0.f, 0.f, 0.f);
    if (n0 + node < N) v = ((const float4*)(hidden + (size_t)(n0 + node) * 64))[i & 15];
    float* hp = &H[node * 65 + k4];
    hp[0] = v.x; hp[1] = v.y; hp[2] = v.z; hp[3] = v.w;
  }
  __syncthreads();

  float acc[16];
  #pragma unroll
  for (int i = 0; i < 16; ++i) acc[i] = scq[g * 16 + i];
  #pragma unroll 8
  for (int kk = 0; kk < 64; ++kk) {
    float h = H[lane * 65 + kk];
    const float4* wr = (const float4*)&WA[kk * 64 + g * 16];
    float4 w0 = wr[0], w1 = wr[1], w2 = wr[2], w3 = wr[3];
    acc[0]  += h * w0.x; acc[1]  += h * w0.y; acc[2]  += h * w0.z; acc[3]  += h * w0.w;
    acc[4]  += h * w1.x; acc[5]  += h * w1.y; acc[6]  += h * w1.z; acc[7]  += h * w1.w;
    acc[8]  += h * w2.x; acc[9]  += h * w2.y; acc[10] += h * w2.z; acc[11] += h * w2.w;
    acc[12] += h * w3.x; acc[13] += h * w3.y; acc[14] += h * w3.z; acc[15] += h * w3.w;
  }
  #pragma unroll
  for (int i = 0; i < 16; ++i) {
    int j = g * 16 + i;
    X[lane * 65 + j] = H[lane * 65 + j] * acc[i];
  }
  __syncthreads();

  for (int i = t; i < 2048; i += 256) ((float4*)W1s)[i] = ((const float4*)mlp_W1)[i];
  __syncthreads();

  float acc2[32];
  #pragma unroll
  for (int i = 0; i < 32; ++i) acc2[i] = sb1[g * 32 + i];
  #pragma unroll 4
  for (int kk = 0; kk < 64; ++kk) {
    float xv = X[lane * 65 + kk];
    const float4* wr = (const float4*)&W1s[kk * 128 + g * 32];
    #pragma unroll
    for (int s = 0; s < 8; ++s) {
      float4 w = wr[s];
      acc2[s * 4 + 0] += xv * w.x; acc2[s * 4 + 1] += xv * w.y;
      acc2[s * 4 + 2] += xv * w.z; acc2[s * 4 + 3] += xv * w.w;
    }
  }
  float p = 0.f;
  #pragma unroll
  for (int i = 0; i < 32; ++i) p += fmaxf(acc2[i], 0.f) * sW2[g * 32 + i];
  pred[g * 64 + lane] = p;
  __syncthreads();
  if (t < 64) {
    int node = n0 + t;
    if (node < N && deg[node] > 0)
      score[node] = pred[t] + pred[64 + t] + pred[128 + t] + pred[192 + t] + mlp_b2[0];
  }
}

__global__ void out_k(const float* __restrict__ score, const int* __restrict__ t_index,
                      float* __restrict__ out, int T) {
  int i = blockIdx.x * blockDim.x + threadIdx.x;
  if (i < T) out[i] = score[t_index[i]];
}

// ---------------- launch ----------------
extern "C" void kernel_launch(void* const* d_in, const int* in_sizes, int n_in,
                              void* d_out, int out_size, void* d_ws, size_t ws_size,
                              hipStream_t stream) {
  const float* head_embeds = (const float*)d_in[0];
  const float* rel_table   = (const float*)d_in[1];
  const float* rel_W       = (const float*)d_in[2];
  const float* agg_W       = (const float*)d_in[3];
  const float* agg_b       = (const float*)d_in[4];
  const float* lin_W       = (const float*)d_in[5];
  const float* lin_b       = (const float*)d_in[6];
  const float* mlp_W1      = (const float*)d_in[7];
  const float* mlp_b1      = (const float*)d_in[8];
  const float* mlp_W2      = (const float*)d_in[9];
  const float* mlp_b2      = (const float*)d_in[10];
  const int* edge_src      = (const int*)d_in[11];
  const int* edge_dst      = (const int*)d_in[12];
  const int* edge_type     = (const int*)d_in[13];
  const int* head_index    = (const int*)d_in[14];
  const int* r_index       = (const int*)d_in[15];
  const int* t_index       = (const int*)d_in[16];
  int E = in_sizes[11];
  int T = in_sizes[16];
  int N = NN;

  char* w = (char*)d_ws;
  size_t off = 0;
  auto alloc = [&](size_t bytes) {
    void* p = w + off;
    off = (off + bytes + 255) & ~(size_t)255;
    return p;
  };
  int* deg      = (int*)alloc((size_t)N * 4);
  int* start    = (int*)alloc((size_t)N * 4);
  int* cursor   = (int*)alloc((size_t)N * 4);
  float* scale  = (float*)alloc((size_t)N * 4);
  int* counter  = (int*)alloc(4);
  float* logsum = (float*)alloc(4);
  float* scalars= (float*)alloc(66 * 4);
  int2* csr     = (int2*)alloc((size_t)E * 8);
  float* hidden = (float*)alloc((size_t)N * 64 * 4);
  float* score  = (float*)alloc((size_t)N * 4);
  float* LI     = (float*)alloc((size_t)N * 64 * 4);
  float* f1     = (float*)alloc((size_t)N * 256 * 4);
  unsigned short* WT = (unsigned short*)alloc((size_t)3 * 4 * 64 * 256 * 2);
  if (off > ws_size) return;  // workspace too small -> fail loudly via wrong output

  hipMemsetAsync(deg, 0, (size_t)N * 4, stream);
  hipMemsetAsync(counter, 0, 4, stream);
  hipMemsetAsync(logsum, 0, 4, stream);
  hipMemsetAsync(hidden, 0, (size_t)N * 64 * 4, stream);

  count_k<<<(E + 255) / 256, 256, 0, stream>>>(edge_dst, deg, E);
  scan_k<<<(N + 255) / 256, 256, 0, stream>>>(deg, start, cursor, counter, logsum, N);
  scale_k<<<(N + 255) / 256, 256, 0, stream>>>(deg, logsum, scale, N);
  scatter_k<<<(E + 255) / 256, 256, 0, stream>>>(edge_src, edge_dst, edge_type, cursor, csr, E);
  wconv_k<<<(3 * 64 * 256 + 255) / 256, 256, 0, stream>>>(agg_W, WT);
  prep_k<<<1, 64, 0, stream>>>(head_embeds, rel_table, lin_W, lin_b, mlp_W1, mlp_b1, mlp_W2, mlp_b2,
                               head_index, r_index, hidden, scalars);
  fill_k<<<(N + 255) / 256, 256, 0, stream>>>(score, scalars, head_index, N);

  for (int l = 0; l < NLAYERS; ++l) {
    gate_k<<<(N * 16 + 255) / 256, 256, 0, stream>>>(hidden, score, LI, N);
    agg_k<<<(N + 3) / 4, 256, 0, stream>>>(LI, csr, start, deg, rel_W + (size_t)l * NREL * 64, f1, N);
    gemm_k<<<(N + 63) / 64, 256, 0, stream>>>(f1, WT + (size_t)l * 4 * 64 * 256,
                                              agg_b + (size_t)l * 64, scale, deg, hidden, N);
    score2_k<<<(N + 63) / 64, 256, 0, stream>>>(hidden, score, deg, lin_W, mlp_W1, mlp_b1, mlp_W2, mlp_b2,
                                                scalars, N);
  }
  out_k<<<(T + 255) / 256, 256, 0, stream>>>(score, t_index, (float*)d_out, T);
}